// Round 1
// baseline (2278.739 us; speedup 1.0000x reference)
//
#include <hip/hip_runtime.h>
#include <hip/hip_bf16.h>

typedef _Float16 half8 __attribute__((ext_vector_type(8)));
typedef float    floatx4 __attribute__((ext_vector_type(4)));

#define B_TOT 4096
#define L_SEQ 2048
#define H_DIM 256
#define FUT   128
#define T_TOT (L_SEQ + FUT)   /* 2176 */
#define ROWS  16              /* batch rows per block */
#define CHUNK 128             /* x prefetch chunk (steps) */

__device__ __forceinline__ float tanh_fast(float p) {
    // tanh(p) = (e^{2p}-1)/(e^{2p}+1); clamp to avoid inf/inf
    p = fminf(fmaxf(p, -9.0f), 9.0f);
    float e = __builtin_amdgcn_exp2f(p * 2.885390082f);   // 2^(2p*log2e) = e^(2p)
    return (e - 1.0f) * __builtin_amdgcn_rcpf(e + 1.0f);
}

__global__ __launch_bounds__(512, 2) void rnn_seq_kernel(
    const float* __restrict__ x,      // [B, L]
    const float* __restrict__ W_ih,   // [H,1] -> [H]
    const float* __restrict__ b_ih,   // [H]
    const float* __restrict__ W_hh,   // [H, H] row-major (out, in)
    const float* __restrict__ b_hh,   // [H]
    const float* __restrict__ W_lin,  // [1,H] -> [H]
    const float* __restrict__ b_lin,  // [1]
    float* __restrict__ out)          // [B, T_TOT]
{
    __shared__ __align__(16) unsigned char hbuf[2][ROWS * H_DIM * 2]; // fp16, dbuf
    __shared__ __align__(16) float xbuf[CHUNK * ROWS];                // [t_local][row]
    __shared__ __align__(16) float obuf[ROWS];

    const int tid  = threadIdx.x;
    const int l    = tid & 63;
    const int w    = tid >> 6;       // wave 0..7
    const int ln15 = l & 15;
    const int lg   = l >> 4;         // 0..3
    const int b0   = blockIdx.x * ROWS;

    // ---------------- loop-invariant register state ----------------
    // W_hh B-fragments: 2 N-tiles per wave, 8 K-steps each.
    // B-frag layout: lane supplies B[k][n] with n = tile*16 + (l&15),
    // k = kk*32 + (l>>4)*8 + j  (8 consecutive k). B[k][n] = W_hh[n][k].
    half8 wf[2][8];
    #pragma unroll
    for (int i = 0; i < 2; ++i) {
        const int n = (2 * w + i) * 16 + ln15;
        #pragma unroll
        for (int kk = 0; kk < 8; ++kk) {
            const float* p = W_hh + n * H_DIM + kk * 32 + lg * 8;
            half8 v;
            #pragma unroll
            for (int j = 0; j < 8; ++j) v[j] = (_Float16)p[j];
            wf[i][kk] = v;
        }
    }
    float wih[2], bia[2];
    #pragma unroll
    for (int i = 0; i < 2; ++i) {
        const int n = (2 * w + i) * 16 + ln15;
        wih[i] = W_ih[n];
        bia[i] = b_ih[n] + b_hh[n];
    }
    // lin: 32 threads per row, 8 k-elems each
    const int lrow = tid >> 5;            // 0..15
    const int lk   = (tid & 31) * 8;
    float wl[8];
    #pragma unroll
    for (int j = 0; j < 8; ++j) wl[j] = W_lin[lk + j];
    const float blin = b_lin[0];

    // Precomputed LDS byte offsets (XOR swizzle: byte ^= (row&7)<<4)
    int aoff[8];
    #pragma unroll
    for (int kk = 0; kk < 8; ++kk)
        aoff[kk] = (ln15 * 512 + kk * 64 + lg * 16) ^ ((ln15 & 7) << 4);
    const int loff = (lrow * 512 + (tid & 31) * 16) ^ ((lrow & 7) << 4);
    int woff[2][4];
    #pragma unroll
    for (int i = 0; i < 2; ++i) {
        #pragma unroll
        for (int r = 0; r < 4; ++r) {
            const int m = lg * 4 + r;
            const int n = (2 * w + i) * 16 + ln15;
            woff[i][r] = (m * 512 + n * 2) ^ ((m & 7) << 4);
        }
    }

    // h0 = 0
    *(floatx4*)(hbuf[0] + tid * 16) = floatx4{0.f, 0.f, 0.f, 0.f};
    __syncthreads();

    int cur = 0;

    // ============================ main phase ============================
    for (int s = 1; s <= L_SEQ; ++s) {
        const int t    = s - 1;
        const int tloc = t & (CHUNK - 1);
        if (tloc == 0) {
            #pragma unroll
            for (int jj = 0; jj < 4; ++jj) {
                const int tt = (tid & 31) + 32 * jj;
                xbuf[tt * ROWS + lrow] = x[(b0 + lrow) * L_SEQ + t + tt];
            }
            __syncthreads();
        }
        // A-fragments of h_{s-1}
        half8 a[8];
        #pragma unroll
        for (int kk = 0; kk < 8; ++kk)
            a[kk] = *(const half8*)(hbuf[cur] + aoff[kk]);
        // lin(h_{s-1}) = out[s-2]
        {
            half8 hv = *(const half8*)(hbuf[cur] + loff);
            float dot = 0.f;
            #pragma unroll
            for (int j = 0; j < 8; ++j) dot += (float)hv[j] * wl[j];
            #pragma unroll
            for (int m = 1; m < 32; m <<= 1) dot += __shfl_xor(dot, m, 32);
            if ((tid & 31) == 0 && s >= 2)
                out[(b0 + lrow) * T_TOT + (s - 2)] = dot + blin;
        }
        // GEMM: C[16,256] = h @ W_hh^T  (2 acc chains per tile for ILP)
        floatx4 acc[2][2];
        acc[0][0] = floatx4{0,0,0,0}; acc[0][1] = floatx4{0,0,0,0};
        acc[1][0] = floatx4{0,0,0,0}; acc[1][1] = floatx4{0,0,0,0};
        #pragma unroll
        for (int kk = 0; kk < 8; ++kk) {
            acc[0][kk & 1] = __builtin_amdgcn_mfma_f32_16x16x32_f16(a[kk], wf[0][kk], acc[0][kk & 1], 0, 0, 0);
            acc[1][kk & 1] = __builtin_amdgcn_mfma_f32_16x16x32_f16(a[kk], wf[1][kk], acc[1][kk & 1], 0, 0, 0);
        }
        // epilogue: + x*W_ih + biases, tanh, fp16 -> hbuf[cur^1]
        const floatx4 xm = *(const floatx4*)(xbuf + tloc * ROWS + lg * 4);
        #pragma unroll
        for (int i = 0; i < 2; ++i) {
            const floatx4 av = acc[i][0] + acc[i][1];
            #pragma unroll
            for (int r = 0; r < 4; ++r) {
                const float pre = av[r] + xm[r] * wih[i] + bia[i];
                *(_Float16*)(hbuf[cur ^ 1] + woff[i][r]) = (_Float16)tanh_fast(pre);
            }
        }
        __syncthreads();
        cur ^= 1;
    }

    // ============================ future phase ============================
    for (int s = L_SEQ + 1; s <= T_TOT; ++s) {
        half8 a[8];
        #pragma unroll
        for (int kk = 0; kk < 8; ++kk)
            a[kk] = *(const half8*)(hbuf[cur] + aoff[kk]);
        // o = lin(h_{s-1}) = out[s-2]  (also the feedback input of this step)
        {
            half8 hv = *(const half8*)(hbuf[cur] + loff);
            float dot = 0.f;
            #pragma unroll
            for (int j = 0; j < 8; ++j) dot += (float)hv[j] * wl[j];
            #pragma unroll
            for (int m = 1; m < 32; m <<= 1) dot += __shfl_xor(dot, m, 32);
            if ((tid & 31) == 0) {
                const float ov = dot + blin;
                out[(b0 + lrow) * T_TOT + (s - 2)] = ov;
                obuf[lrow] = ov;
            }
        }
        floatx4 acc[2][2];
        acc[0][0] = floatx4{0,0,0,0}; acc[0][1] = floatx4{0,0,0,0};
        acc[1][0] = floatx4{0,0,0,0}; acc[1][1] = floatx4{0,0,0,0};
        #pragma unroll
        for (int kk = 0; kk < 8; ++kk) {
            acc[0][kk & 1] = __builtin_amdgcn_mfma_f32_16x16x32_f16(a[kk], wf[0][kk], acc[0][kk & 1], 0, 0, 0);
            acc[1][kk & 1] = __builtin_amdgcn_mfma_f32_16x16x32_f16(a[kk], wf[1][kk], acc[1][kk & 1], 0, 0, 0);
        }
        __syncthreads();   // obuf visible
        const floatx4 om = *(const floatx4*)(obuf + lg * 4);
        #pragma unroll
        for (int i = 0; i < 2; ++i) {
            const floatx4 av = acc[i][0] + acc[i][1];
            #pragma unroll
            for (int r = 0; r < 4; ++r) {
                const float pre = av[r] + om[r] * wih[i] + bia[i];
                *(_Float16*)(hbuf[cur ^ 1] + woff[i][r]) = (_Float16)tanh_fast(pre);
            }
        }
        __syncthreads();
        cur ^= 1;
    }

    // final output column: out[:, T_TOT-1] = lin(h_final)
    {
        half8 hv = *(const half8*)(hbuf[cur] + loff);
        float dot = 0.f;
        #pragma unroll
        for (int j = 0; j < 8; ++j) dot += (float)hv[j] * wl[j];
        #pragma unroll
        for (int m = 1; m < 32; m <<= 1) dot += __shfl_xor(dot, m, 32);
        if ((tid & 31) == 0)
            out[(b0 + lrow) * T_TOT + (T_TOT - 1)] = dot + blin;
    }
}

extern "C" void kernel_launch(void* const* d_in, const int* in_sizes, int n_in,
                              void* d_out, int out_size, void* d_ws, size_t ws_size,
                              hipStream_t stream) {
    const float* x     = (const float*)d_in[0];
    const float* W_ih  = (const float*)d_in[1];
    const float* b_ih  = (const float*)d_in[2];
    const float* W_hh  = (const float*)d_in[3];
    const float* b_hh  = (const float*)d_in[4];
    const float* W_lin = (const float*)d_in[5];
    const float* b_lin = (const float*)d_in[6];
    float* out = (float*)d_out;
    rnn_seq_kernel<<<B_TOT / ROWS, 512, 0, stream>>>(x, W_ih, b_ih, W_hh, b_hh, W_lin, b_lin, out);
}

// Round 2
// 1683.786 us; speedup vs baseline: 1.3533x; 1.3533x over previous
//
#include <hip/hip_runtime.h>
#include <hip/hip_bf16.h>

typedef _Float16 half8 __attribute__((ext_vector_type(8)));
typedef _Float16 half4 __attribute__((ext_vector_type(4)));
typedef float    floatx4 __attribute__((ext_vector_type(4)));

#define B_TOT 4096
#define L_SEQ 2048
#define H_DIM 256
#define FUT   128
#define T_TOT (L_SEQ + FUT)   /* 2176 */
#define ROWS  16              /* batch rows per block */
#define CHUNK 128             /* x prefetch chunk (steps) */

__device__ __forceinline__ float tanh_fast(float p) {
    p = fminf(fmaxf(p, -9.0f), 9.0f);
    float e = __builtin_amdgcn_exp2f(p * 2.885390082f);   // e^(2p)
    return (e - 1.0f) * __builtin_amdgcn_rcpf(e + 1.0f);
}

// Swapped-operand step GEMM: C = W_tile(A) @ h^T(B).
//   A-frag (lane ln15,lg): W[tile*16+ln15][kk*32+lg*8+j]   (loop-invariant regs)
//   B-frag (lane ln15,lg): h[ln15][kk*32+lg*8+j]           (ds_read_b128, swizzled)
//   C-frag: col = ln15 = batch row m; row = lg*4+r = n-within-tile
//   -> epilogue writes 4 consecutive n at fixed m: one ds_write_b64 per tile.
// lin(h) = 17th A-tile (W_lin in row 0) on wave 0; outs ring-buffered in LDS,
// flushed coalesced every 32 steps (no per-step global store -> no vmcnt drain
// at the per-step barrier).
__global__ __launch_bounds__(512, 2) void rnn_seq_kernel(
    const float* __restrict__ x,      // [B, L]
    const float* __restrict__ W_ih,   // [H]
    const float* __restrict__ b_ih,   // [H]
    const float* __restrict__ W_hh,   // [H, H]
    const float* __restrict__ b_hh,   // [H]
    const float* __restrict__ W_lin,  // [H]
    const float* __restrict__ b_lin,  // [1]
    float* __restrict__ out)          // [B, T_TOT]
{
    __shared__ __align__(16) unsigned char hbuf[2][ROWS * H_DIM * 2]; // fp16 dbuf
    __shared__ __align__(16) float xbuf[CHUNK * 17];                  // [t_local][row], padded
    __shared__ __align__(16) float obuf2[2][32][17];                  // out ring, padded

    const int tid  = threadIdx.x;
    const int l    = tid & 63;
    const int w    = tid >> 6;       // wave 0..7
    const int ln15 = l & 15;
    const int lg   = l >> 4;         // 0..3
    const int b0   = blockIdx.x * ROWS;

    // ---- loop-invariant register state ----
    half8 wf[2][8];                   // W_hh A-frags: 2 tiles/wave
    #pragma unroll
    for (int i = 0; i < 2; ++i) {
        const int n = (2 * w + i) * 16 + ln15;
        #pragma unroll
        for (int kk = 0; kk < 8; ++kk) {
            const float* p = W_hh + n * H_DIM + kk * 32 + lg * 8;
            half8 v;
            #pragma unroll
            for (int j = 0; j < 8; ++j) v[j] = (_Float16)p[j];
            wf[i][kk] = v;
        }
    }
    half8 wlf[8];                     // W_lin A-frag (row 0 only), used by wave 0
    #pragma unroll
    for (int kk = 0; kk < 8; ++kk) {
        const int kbase = kk * 32 + lg * 8;
        half8 v;
        #pragma unroll
        for (int j = 0; j < 8; ++j)
            v[j] = (ln15 == 0) ? (_Float16)W_lin[kbase + j] : (_Float16)0.0f;
        wlf[kk] = v;
    }
    floatx4 wih4[2], bia4[2];         // n-indexed per-thread epilogue constants
    #pragma unroll
    for (int i = 0; i < 2; ++i) {
        const int n0 = (2 * w + i) * 16 + lg * 4;
        #pragma unroll
        for (int r = 0; r < 4; ++r) {
            wih4[i][r] = W_ih[n0 + r];
            bia4[i][r] = b_ih[n0 + r] + b_hh[n0 + r];
        }
    }
    const float blin = b_lin[0];
    float wl[8];                      // for the one final lin after the loop
    #pragma unroll
    for (int j = 0; j < 8; ++j) wl[j] = W_lin[(tid & 31) * 8 + j];

    // LDS byte offsets (XOR swizzle on bits 4-6 keyed by row m&7)
    int aoff[8];
    #pragma unroll
    for (int kk = 0; kk < 8; ++kk)
        aoff[kk] = (ln15 * 512 + kk * 64 + lg * 16) ^ ((ln15 & 7) << 4);
    int woff2[2];
    #pragma unroll
    for (int i = 0; i < 2; ++i)
        woff2[i] = (ln15 * 512 + (2 * w + i) * 32 + lg * 8) ^ ((ln15 & 7) << 4);

    *(floatx4*)(hbuf[0] + tid * 16) = floatx4{0.f, 0.f, 0.f, 0.f};  // h0 = 0
    __syncthreads();

    int cur = 0;
    for (int s = 1; s <= T_TOT; ++s) {
        const int t_out = s - 2;      // out index produced by this step's GEMM

        // coalesced flush of the completed 32-out block (parity-safe: the
        // block being flushed lives in the opposite ring half from this
        // step's write)
        if (t_out >= 32 && (t_out & 31) == 0) {
            const int tb = t_out - 32, par = (tb >> 5) & 1;
            const int row = tid >> 5, tt = tid & 31;
            out[(size_t)(b0 + row) * T_TOT + tb + tt] = obuf2[par][tt][row] + blin;
        }

        const bool fut = (s > L_SEQ);
        if (!fut && ((s - 1) & (CHUNK - 1)) == 0) {   // x chunk prefetch
            #pragma unroll
            for (int jj = 0; jj < 4; ++jj) {
                const int idx = jj * 512 + tid;
                const int row = idx >> 7, tl = idx & 127;
                xbuf[tl * 17 + row] = x[(size_t)(b0 + row) * L_SEQ + (s - 1) + tl];
            }
            __syncthreads();
        }

        // B-frags of h_{s-1}
        half8 a[8];
        #pragma unroll
        for (int kk = 0; kk < 8; ++kk)
            a[kk] = *(const half8*)(hbuf[cur] + aoff[kk]);

        // GEMM (bias folded into acc chain 0 init)
        floatx4 acc[2][2];
        acc[0][0] = bia4[0]; acc[0][1] = floatx4{0,0,0,0};
        acc[1][0] = bia4[1]; acc[1][1] = floatx4{0,0,0,0};
        #pragma unroll
        for (int kk = 0; kk < 8; ++kk) {
            acc[0][kk & 1] = __builtin_amdgcn_mfma_f32_16x16x32_f16(wf[0][kk], a[kk], acc[0][kk & 1], 0, 0, 0);
            acc[1][kk & 1] = __builtin_amdgcn_mfma_f32_16x16x32_f16(wf[1][kk], a[kk], acc[1][kk & 1], 0, 0, 0);
        }
        // lin tile on wave 0: C row 0 = lin(h_{s-1}) = out[s-2] (sans b_lin)
        if (w == 0) {
            floatx4 al0 = floatx4{0,0,0,0}, al1 = floatx4{0,0,0,0};
            #pragma unroll
            for (int kk = 0; kk < 8; ++kk) {
                if (kk & 1) al1 = __builtin_amdgcn_mfma_f32_16x16x32_f16(wlf[kk], a[kk], al1, 0, 0, 0);
                else        al0 = __builtin_amdgcn_mfma_f32_16x16x32_f16(wlf[kk], a[kk], al0, 0, 0, 0);
            }
            if (lg == 0 && s >= 2)
                obuf2[(t_out >> 5) & 1][t_out & 31][ln15] = al0[0] + al1[0];
        }

        // per-row step input: x_t (main) or fed-back output (future)
        float xm;
        if (fut) {
            __syncthreads();   // obuf2 (this step's lin) visible to all waves
            xm = obuf2[(t_out >> 5) & 1][t_out & 31][ln15] + blin;
        } else {
            xm = xbuf[((s - 1) & (CHUNK - 1)) * 17 + ln15];
        }

        // epilogue: tanh + packed b64 h-write
        #pragma unroll
        for (int i = 0; i < 2; ++i) {
            const floatx4 av = acc[i][0] + acc[i][1];
            half4 hv;
            #pragma unroll
            for (int r = 0; r < 4; ++r)
                hv[r] = (_Float16)tanh_fast(av[r] + xm * wih4[i][r]);
            *(half4*)(hbuf[cur ^ 1] + woff2[i]) = hv;
        }
        __syncthreads();
        cur ^= 1;
    }

    // final out: t = 2175 = lin(h_2176) -> ring slot [1][31]
    {
        const int m = tid >> 5, kb = (tid & 31) * 8;
        const int off = (m * 512 + kb * 2) ^ ((m & 7) << 4);
        const half8 hv = *(const half8*)(hbuf[cur] + off);
        float dot = 0.f;
        #pragma unroll
        for (int j = 0; j < 8; ++j) dot += (float)hv[j] * wl[j];
        #pragma unroll
        for (int msk = 1; msk < 32; msk <<= 1) dot += __shfl_xor(dot, msk, 32);
        if ((tid & 31) == 0) obuf2[1][31][m] = dot;
    }
    __syncthreads();
    {   // final flush t = 2144..2175 (parity 1)
        const int row = tid >> 5, tt = tid & 31;
        out[(size_t)(b0 + row) * T_TOT + 2144 + tt] = obuf2[1][tt][row] + blin;
    }
}

extern "C" void kernel_launch(void* const* d_in, const int* in_sizes, int n_in,
                              void* d_out, int out_size, void* d_ws, size_t ws_size,
                              hipStream_t stream) {
    const float* x     = (const float*)d_in[0];
    const float* W_ih  = (const float*)d_in[1];
    const float* b_ih  = (const float*)d_in[2];
    const float* W_hh  = (const float*)d_in[3];
    const float* b_hh  = (const float*)d_in[4];
    const float* W_lin = (const float*)d_in[5];
    const float* b_lin = (const float*)d_in[6];
    float* out = (float*)d_out;
    rnn_seq_kernel<<<B_TOT / ROWS, 512, 0, stream>>>(x, W_ih, b_ih, W_hh, b_hh, W_lin, b_lin, out);
}